// Round 1
// baseline (1246.890 us; speedup 1.0000x reference)
//
#include <hip/hip_runtime.h>
#include <math.h>

#define N_ROWS 65536
#define ZDIM   256
#define KCODES 1024
#define IDX_OFF  (N_ROWS * ZDIM)        // 16777216
#define LOSS_OFF (IDX_OFF + N_ROWS)     // 16842752

// ---------------- numpy-pairwise row sum of squares (256 cols) ----------------
// Reproduces numpy pairwise_sum for n=256: split 128+128; each 128 via 8
// accumulators striding 8, combined ((r0+r1)+(r2+r3))+((r4+r5)+(r6+r7)).
// __fmul_rn/__fadd_rn block fp-contract so rounding matches np (square rounds
// first, then add).
__device__ __forceinline__ float np_pw128_sq(const float* __restrict__ p) {
    float r[8];
#pragma unroll
    for (int j = 0; j < 8; ++j) r[j] = __fmul_rn(p[j], p[j]);
    for (int i = 8; i < 128; i += 8) {
#pragma unroll
        for (int j = 0; j < 8; ++j)
            r[j] = __fadd_rn(r[j], __fmul_rn(p[i + j], p[i + j]));
    }
    float a = __fadd_rn(__fadd_rn(r[0], r[1]), __fadd_rn(r[2], r[3]));
    float b = __fadd_rn(__fadd_rn(r[4], r[5]), __fadd_rn(r[6], r[7]));
    return __fadd_rn(a, b);
}

__global__ void rowsq_kernel(const float* __restrict__ x, float* __restrict__ s, int nrows) {
    int r = blockIdx.x * blockDim.x + threadIdx.x;
    if (r >= nrows) return;
    const float* p = x + (size_t)r * ZDIM;
    s[r] = __fadd_rn(np_pw128_sq(p), np_pw128_sq(p + 128));
}

// ---------------- main distance + argmin kernel ----------------
// Block: 256 threads (16x16), 128 rows. Loops 8 code-tiles of 128 codes,
// K=256 staged in 8 chunks of 32 dims. Each thread: 8 rows x 8 codes.
// Dot accumulated with sequential-k fmaf chain (matches BLAS microkernel
// accumulation order bit-exactly). d = fl(fl(sz+se) - 2*m), argmin keeps
// FIRST minimal index (np.argmin semantics), including post-rounding ties.
__global__ __launch_bounds__(256) void argmin_kernel(
    const float* __restrict__ z, const float* __restrict__ e,
    const float* __restrict__ sz, const float* __restrict__ se,
    int* __restrict__ out_idx, float* __restrict__ out_idx_f) {
    __shared__ float zt[32][132];
    __shared__ float et[32][132];
    const int tid = threadIdx.x;
    const int tc = tid & 15;
    const int tr = tid >> 4;
    const int br0 = blockIdx.x * 128;

    float szr[8];
#pragma unroll
    for (int r = 0; r < 8; ++r) szr[r] = sz[br0 + tr * 8 + r];

    float bestd[8];
    int   besti[8];
#pragma unroll
    for (int r = 0; r < 8; ++r) { bestd[r] = __builtin_inff(); besti[r] = 0; }

    for (int ct = 0; ct < 8; ++ct) {
        const int c0 = ct * 128;
        float acc[8][8];
#pragma unroll
        for (int r = 0; r < 8; ++r)
#pragma unroll
            for (int c = 0; c < 8; ++c) acc[r][c] = 0.0f;

        for (int kc = 0; kc < 8; ++kc) {
            const int kb = kc * 32;
            __syncthreads();
#pragma unroll
            for (int it = 0; it < 4; ++it) {
                int flat = it * 256 + tid;   // 0..1023
                int row  = flat >> 3;        // 0..127
                int q    = flat & 7;         // float4 index within 32 dims
                float4 vz = *(const float4*)(z + (size_t)(br0 + row) * ZDIM + kb + q * 4);
                float4 ve = *(const float4*)(e + (size_t)(c0 + row) * ZDIM + kb + q * 4);
                zt[q * 4 + 0][row] = vz.x; zt[q * 4 + 1][row] = vz.y;
                zt[q * 4 + 2][row] = vz.z; zt[q * 4 + 3][row] = vz.w;
                et[q * 4 + 0][row] = ve.x; et[q * 4 + 1][row] = ve.y;
                et[q * 4 + 2][row] = ve.z; et[q * 4 + 3][row] = ve.w;
            }
            __syncthreads();
            for (int k = 0; k < 32; ++k) {
                float4 za = *(const float4*)&zt[k][tr * 8];
                float4 zb = *(const float4*)&zt[k][tr * 8 + 4];
                float4 ea = *(const float4*)&et[k][tc * 8];
                float4 eb = *(const float4*)&et[k][tc * 8 + 4];
                float zf[8] = {za.x, za.y, za.z, za.w, zb.x, zb.y, zb.z, zb.w};
                float ef[8] = {ea.x, ea.y, ea.z, ea.w, eb.x, eb.y, eb.z, eb.w};
#pragma unroll
                for (int r = 0; r < 8; ++r)
#pragma unroll
                    for (int c = 0; c < 8; ++c)
                        acc[r][c] = fmaf(zf[r], ef[c], acc[r][c]);
            }
        }
        // epilogue for this code tile: codes visited in ascending order
#pragma unroll
        for (int c = 0; c < 8; ++c) {
            int code = c0 + tc * 8 + c;
            float sec = se[code];
#pragma unroll
            for (int r = 0; r < 8; ++r) {
                float t = __fadd_rn(szr[r], sec);
                float d = __fsub_rn(t, 2.0f * acc[r][c]);
                if (d < bestd[r]) { bestd[r] = d; besti[r] = code; }
            }
        }
    }

    // cross-thread reduction: lexicographic (d, idx) min == first-occurrence argmin
    __syncthreads();
    float2* red = (float2*)&zt[0][0];   // 128*16 float2 = 16 KB, fits in zt
#pragma unroll
    for (int r = 0; r < 8; ++r)
        red[(tr * 8 + r) * 16 + tc] = make_float2(bestd[r], (float)besti[r]);
    __syncthreads();
    if (tid < 128) {
        float bd = __builtin_inff();
        float bi = 0.0f;
        for (int t = 0; t < 16; ++t) {
            float2 v = red[tid * 16 + t];
            if (v.x < bd || (v.x == bd && v.y < bi)) { bd = v.x; bi = v.y; }
        }
        out_idx[br0 + tid]   = (int)bi;
        out_idx_f[br0 + tid] = bi;       // harness reads whole out buf as f32
    }
}

// ---------------- z_q_st + loss partial ----------------
__global__ __launch_bounds__(256) void zq_loss_kernel(
    const float* __restrict__ z, const float* __restrict__ e,
    const int* __restrict__ idx, float* __restrict__ out,
    double* __restrict__ lsum) {
    int row = blockIdx.x;
    int j = threadIdx.x;
    int code = idx[row];
    float zv = z[(size_t)row * ZDIM + j];
    float qv = e[(size_t)code * ZDIM + j];
    float diff = __fsub_rn(qv, zv);
    out[(size_t)row * ZDIM + j] = __fadd_rn(zv, diff);  // z + (q - z), fp32 per-op
    float sq = __fmul_rn(diff, diff);
#pragma unroll
    for (int off = 32; off; off >>= 1) sq += __shfl_down(sq, off, 64);
    __shared__ float part[4];
    if ((j & 63) == 0) part[j >> 6] = sq;
    __syncthreads();
    if (j == 0) {
        float s = ((part[0] + part[1]) + (part[2] + part[3]));
        atomicAdd(lsum, (double)s);
    }
}

__global__ void loss_final_kernel(const double* __restrict__ lsum,
                                  float* __restrict__ out_loss) {
    double M = lsum[0] / 16777216.0;
    float m32 = (float)M;
    out_loss[0] = __fadd_rn(m32, __fmul_rn(0.25f, m32));  // mean + 0.25*mean
}

extern "C" void kernel_launch(void* const* d_in, const int* in_sizes, int n_in,
                              void* d_out, int out_size, void* d_ws, size_t ws_size,
                              hipStream_t stream) {
    const float* z = (const float*)d_in[0];
    const float* e = (const float*)d_in[1];
    float* out = (float*)d_out;
    char* ws = (char*)d_ws;

    double* lsum = (double*)ws;                                   // 8 B
    float*  sz   = (float*)(ws + 16);                             // 256 KB
    float*  se   = (float*)(ws + 16 + (size_t)N_ROWS * 4);        // 4 KB
    int*    idx  = (int*)  (ws + 16 + (size_t)N_ROWS * 4 + (size_t)KCODES * 4);

    hipMemsetAsync(lsum, 0, 16, stream);
    rowsq_kernel<<<N_ROWS / 256, 256, 0, stream>>>(z, sz, N_ROWS);
    rowsq_kernel<<<KCODES / 256, 256, 0, stream>>>(e, se, KCODES);
    argmin_kernel<<<N_ROWS / 128, 256, 0, stream>>>(z, e, sz, se, idx, out + IDX_OFF);
    zq_loss_kernel<<<N_ROWS, 256, 0, stream>>>(z, e, idx, out, lsum);
    loss_final_kernel<<<1, 1, 0, stream>>>(lsum, out + LOSS_OFF);
}

// Round 2
// 475.911 us; speedup vs baseline: 2.6200x; 2.6200x over previous
//
#include <hip/hip_runtime.h>
#include <math.h>

#define N_ROWS 65536
#define ZDIM   256
#define KCODES 1024
#define IDX_OFF  (N_ROWS * ZDIM)        // 16777216
#define LOSS_OFF (IDX_OFF + N_ROWS)     // 16842752
#define ZQ_BLOCKS 2048

// ---------------- numpy-pairwise row sum of squares (256 cols) ----------------
// Reproduces numpy pairwise_sum for n=256: split 128+128; each 128 via 8
// accumulators striding 8, combined ((r0+r1)+(r2+r3))+((r4+r5)+(r6+r7)).
__device__ __forceinline__ float np_pw128_sq(const float* __restrict__ p) {
    float r[8];
#pragma unroll
    for (int j = 0; j < 8; ++j) r[j] = __fmul_rn(p[j], p[j]);
    for (int i = 8; i < 128; i += 8) {
#pragma unroll
        for (int j = 0; j < 8; ++j)
            r[j] = __fadd_rn(r[j], __fmul_rn(p[i + j], p[i + j]));
    }
    float a = __fadd_rn(__fadd_rn(r[0], r[1]), __fadd_rn(r[2], r[3]));
    float b = __fadd_rn(__fadd_rn(r[4], r[5]), __fadd_rn(r[6], r[7]));
    return __fadd_rn(a, b);
}

__global__ void rowsq_kernel(const float* __restrict__ x, float* __restrict__ s, int nrows) {
    int r = blockIdx.x * blockDim.x + threadIdx.x;
    if (r >= nrows) return;
    const float* p = x + (size_t)r * ZDIM;
    s[r] = __fadd_rn(np_pw128_sq(p), np_pw128_sq(p + 128));
}

// ---------------- main distance + argmin kernel ----------------
__global__ __launch_bounds__(256) void argmin_kernel(
    const float* __restrict__ z, const float* __restrict__ e,
    const float* __restrict__ sz, const float* __restrict__ se,
    int* __restrict__ out_idx, float* __restrict__ out_idx_f) {
    __shared__ float zt[32][132];
    __shared__ float et[32][132];
    const int tid = threadIdx.x;
    const int tc = tid & 15;
    const int tr = tid >> 4;
    const int br0 = blockIdx.x * 128;

    float szr[8];
#pragma unroll
    for (int r = 0; r < 8; ++r) szr[r] = sz[br0 + tr * 8 + r];

    float bestd[8];
    int   besti[8];
#pragma unroll
    for (int r = 0; r < 8; ++r) { bestd[r] = __builtin_inff(); besti[r] = 0; }

    for (int ct = 0; ct < 8; ++ct) {
        const int c0 = ct * 128;
        float acc[8][8];
#pragma unroll
        for (int r = 0; r < 8; ++r)
#pragma unroll
            for (int c = 0; c < 8; ++c) acc[r][c] = 0.0f;

        for (int kc = 0; kc < 8; ++kc) {
            const int kb = kc * 32;
            __syncthreads();
#pragma unroll
            for (int it = 0; it < 4; ++it) {
                int flat = it * 256 + tid;   // 0..1023
                int row  = flat >> 3;        // 0..127
                int q    = flat & 7;         // float4 index within 32 dims
                float4 vz = *(const float4*)(z + (size_t)(br0 + row) * ZDIM + kb + q * 4);
                float4 ve = *(const float4*)(e + (size_t)(c0 + row) * ZDIM + kb + q * 4);
                zt[q * 4 + 0][row] = vz.x; zt[q * 4 + 1][row] = vz.y;
                zt[q * 4 + 2][row] = vz.z; zt[q * 4 + 3][row] = vz.w;
                et[q * 4 + 0][row] = ve.x; et[q * 4 + 1][row] = ve.y;
                et[q * 4 + 2][row] = ve.z; et[q * 4 + 3][row] = ve.w;
            }
            __syncthreads();
            for (int k = 0; k < 32; ++k) {
                float4 za = *(const float4*)&zt[k][tr * 8];
                float4 zb = *(const float4*)&zt[k][tr * 8 + 4];
                float4 ea = *(const float4*)&et[k][tc * 8];
                float4 eb = *(const float4*)&et[k][tc * 8 + 4];
                float zf[8] = {za.x, za.y, za.z, za.w, zb.x, zb.y, zb.z, zb.w};
                float ef[8] = {ea.x, ea.y, ea.z, ea.w, eb.x, eb.y, eb.z, eb.w};
#pragma unroll
                for (int r = 0; r < 8; ++r)
#pragma unroll
                    for (int c = 0; c < 8; ++c)
                        acc[r][c] = fmaf(zf[r], ef[c], acc[r][c]);
            }
        }
#pragma unroll
        for (int c = 0; c < 8; ++c) {
            int code = c0 + tc * 8 + c;
            float sec = se[code];
#pragma unroll
            for (int r = 0; r < 8; ++r) {
                float t = __fadd_rn(szr[r], sec);
                float d = __fsub_rn(t, 2.0f * acc[r][c]);
                if (d < bestd[r]) { bestd[r] = d; besti[r] = code; }
            }
        }
    }

    __syncthreads();
    float2* red = (float2*)&zt[0][0];
#pragma unroll
    for (int r = 0; r < 8; ++r)
        red[(tr * 8 + r) * 16 + tc] = make_float2(bestd[r], (float)besti[r]);
    __syncthreads();
    if (tid < 128) {
        float bd = __builtin_inff();
        float bi = 0.0f;
        for (int t = 0; t < 16; ++t) {
            float2 v = red[tid * 16 + t];
            if (v.x < bd || (v.x == bd && v.y < bi)) { bd = v.x; bi = v.y; }
        }
        out_idx[br0 + tid]   = (int)bi;
        out_idx_f[br0 + tid] = bi;
    }
}

// ---------------- z_q_st + loss partial (no atomics) ----------------
// 2048 blocks x 256 threads. Each block: 32 rows. Per iteration 4 rows:
// thread t -> local row t>>6, lane (t&63) loads float4. idx[row] is uniform
// across the 64-lane group -> e row read is a coalesced broadcast.
// Per-thread float accumulation in fixed order; per-block fixed-order LDS
// tree reduce in double -> partial[block]. Deterministic.
__global__ __launch_bounds__(256) void zq_loss_kernel(
    const float* __restrict__ z, const float* __restrict__ e,
    const int* __restrict__ idx, float* __restrict__ out,
    double* __restrict__ partial) {
    const int tid = threadIdx.x;
    const int rl  = tid >> 6;        // 0..3 row within iteration group
    const int ln  = tid & 63;        // lane -> float4 slot
    const int row0 = blockIdx.x * 32;

    float acc = 0.0f;
#pragma unroll
    for (int it = 0; it < 8; ++it) {
        int row = row0 + it * 4 + rl;
        int code = idx[row];
        const float4 vz = *(const float4*)(z + (size_t)row  * ZDIM + ln * 4);
        const float4 vq = *(const float4*)(e + (size_t)code * ZDIM + ln * 4);
        float4 o;
        float dx = __fsub_rn(vq.x, vz.x);
        float dy = __fsub_rn(vq.y, vz.y);
        float dz_ = __fsub_rn(vq.z, vz.z);
        float dw = __fsub_rn(vq.w, vz.w);
        o.x = __fadd_rn(vz.x, dx);
        o.y = __fadd_rn(vz.y, dy);
        o.z = __fadd_rn(vz.z, dz_);
        o.w = __fadd_rn(vz.w, dw);
        *(float4*)(out + (size_t)row * ZDIM + ln * 4) = o;
        acc = __fadd_rn(acc, __fmul_rn(dx, dx));
        acc = __fadd_rn(acc, __fmul_rn(dy, dy));
        acc = __fadd_rn(acc, __fmul_rn(dz_, dz_));
        acc = __fadd_rn(acc, __fmul_rn(dw, dw));
    }

    __shared__ double red[256];
    red[tid] = (double)acc;
    __syncthreads();
#pragma unroll
    for (int s = 128; s > 0; s >>= 1) {
        if (tid < s) red[tid] += red[tid + s];
        __syncthreads();
    }
    if (tid == 0) partial[blockIdx.x] = red[0];
}

__global__ __launch_bounds__(256) void loss_final_kernel(
    const double* __restrict__ partial, float* __restrict__ out_loss) {
    const int tid = threadIdx.x;
    double s = 0.0;
    // fixed order: thread t sums partials t, t+256, ... (8 each)
    for (int i = tid; i < ZQ_BLOCKS; i += 256) s += partial[i];
    __shared__ double red[256];
    red[tid] = s;
    __syncthreads();
#pragma unroll
    for (int st = 128; st > 0; st >>= 1) {
        if (tid < st) red[tid] += red[tid + st];
        __syncthreads();
    }
    if (tid == 0) {
        double M = red[0] / 16777216.0;
        float m32 = (float)M;
        out_loss[0] = __fadd_rn(m32, __fmul_rn(0.25f, m32));
    }
}

extern "C" void kernel_launch(void* const* d_in, const int* in_sizes, int n_in,
                              void* d_out, int out_size, void* d_ws, size_t ws_size,
                              hipStream_t stream) {
    const float* z = (const float*)d_in[0];
    const float* e = (const float*)d_in[1];
    float* out = (float*)d_out;
    char* ws = (char*)d_ws;

    double* partial = (double*)ws;                                   // 16 KB
    float*  sz   = (float*)(ws + ZQ_BLOCKS * sizeof(double));        // 256 KB
    float*  se   = (float*)(ws + ZQ_BLOCKS * sizeof(double) + (size_t)N_ROWS * 4);
    int*    idx  = (int*)  (ws + ZQ_BLOCKS * sizeof(double) + (size_t)N_ROWS * 4 + (size_t)KCODES * 4);

    rowsq_kernel<<<N_ROWS / 256, 256, 0, stream>>>(z, sz, N_ROWS);
    rowsq_kernel<<<KCODES / 256, 256, 0, stream>>>(e, se, KCODES);
    argmin_kernel<<<N_ROWS / 128, 256, 0, stream>>>(z, e, sz, se, idx, out + IDX_OFF);
    zq_loss_kernel<<<ZQ_BLOCKS, 256, 0, stream>>>(z, e, idx, out, partial);
    loss_final_kernel<<<1, 256, 0, stream>>>(partial, out + LOSS_OFF);
}